// Round 13
// baseline (142.386 us; speedup 1.0000x reference)
//
#include <hip/hip_runtime.h>

// SingleStageDetector, R22 = R21 (frag-ready F pre-pass, proven correct)
// with both halves restructured for throughput:
//   prep v2: block=(b,k32),128thr: contiguous float4 reads (guaranteed
//     full-line coalescing; R21 used 8 scalar stride-196B loads/thread and
//     relied on L2 half-line merging) -> LDS f32 (6.3KB) -> frag assembly
//     (LDS reads 2 lanes/bank = free) -> coalesced uint4 writes. Barrier-
//     phased is SAFE here: ~41 tiny blocks/CU overlap (the R9-R15 drain
//     problem only bites at 1-4 lock-phased blocks/CU). W-prep folded in.
//   fused v2: grid 512=(image,col-half), 8 waves, 2 independently-phased
//     blocks/CU (tail overlaps neighbor's GEMM1), 4-deep rolling prefetch
//     (k&3 static under full unroll), smHT 32x68. Frag layout, GEMM2,
//     epilogue, IoU unchanged from R21 (absmax 0.0039 verified).

#define CIN_  1280
#define HW_   49
#define HID_  128
#define OUTD_ 65
#define NGT_  40
#define NP_   441

// flat output offsets (elements), reference return order
#define CONF_OFF 0
#define OFFS_OFF 112896   // 256*9*49
#define CLS_OFF  564480   // + 256*9*4*49
#define IOU_OFF  815360   // + 256*20*49 ; total 5,331,200

// ws layout (u32): W1f frags, W2f frags, F frags
#define WS_W1F_U32 81920u
#define WS_W2F_U32 5120u
#define FB_OFF     87040u                  // F-frag: 256*40*4*64 uint4 = 42MB

typedef __bf16 bf16x8 __attribute__((ext_vector_type(8)));
typedef float  f32x4  __attribute__((ext_vector_type(4)));

__device__ __forceinline__ unsigned pack2bf(float lo, float hi) {
    unsigned short a = __builtin_bit_cast(unsigned short, (__bf16)lo);
    unsigned short b = __builtin_bit_cast(unsigned short, (__bf16)hi);
    return (unsigned)a | ((unsigned)b << 16);   // v_cvt_pk_bf16_f32
}
__device__ __forceinline__ float sigmoidf_(float v) { return 1.f / (1.f + __expf(-v)); }

__device__ __forceinline__ bf16x8 ld_frag(const unsigned* p) {
    union { uint4 u; bf16x8 v; } x;
    x.u = *(const uint4*)p;                       // ds_read_b128
    return x.v;
}
__device__ __forceinline__ bf16x8 as_bf(uint4 u) {
    union { uint4 u; bf16x8 v; } x; x.u = u; return x.v;
}

// ---------------------------------------------------------------------------
// prep: blocks [0,10240) = (b*40+k32) F-frag tiles; [10240,10920) W1/W2 frags.
// ---------------------------------------------------------------------------
__global__ __launch_bounds__(128) void prep(
    const float* __restrict__ F,
    const float* __restrict__ W1, const float* __restrict__ W2,
    unsigned* __restrict__ ws)
{
    if (blockIdx.x < 10240) {
        __shared__ __align__(16) float lds[1568];      // 32 ch x 49 col f32
        const int X   = blockIdx.x;                    // b*40 + k32
        const int b   = X / 40;
        const int k32 = X - b * 40;
        const int tid = threadIdx.x;

        // contiguous load: 392 float4 = 6272B, fully coalesced
        const float4* src = (const float4*)(F + b * (CIN_ * HW_) + k32 * 1568);
        float4* dst4 = (float4*)lds;
        dst4[tid]       = src[tid];
        dst4[tid + 128] = src[tid + 128];
        dst4[tid + 256] = src[tid + 256];
        if (tid < 8) dst4[tid + 384] = src[tid + 384];
        __syncthreads();

        // assemble frags: idx = ct*64+lane; thread does idx = tid, tid+128
        uint4* dst = (uint4*)(ws + FB_OFF) + (unsigned)X * 256;
        #pragma unroll
        for (int h2 = 0; h2 < 2; ++h2) {
            int idx  = h2 * 128 + tid;
            int ct   = idx >> 6, lane = idx & 63;
            int quad = lane >> 4, m16 = lane & 15;
            int col  = ct * 16 + m16; if (col > 48) col = 48;
            const float* p = lds + quad * 8 * 49 + col;    // + j*49
            uint4 q;
            q.x = pack2bf(p[0],   p[49]);
            q.y = pack2bf(p[98],  p[147]);
            q.z = pack2bf(p[196], p[245]);
            q.w = pack2bf(p[294], p[343]);
            dst[idx] = q;                                  // coalesced 16B
        }
        return;
    }
    int X = (blockIdx.x - 10240) * 128 + threadIdx.x;   // 0..87039
    if (X < (int)WS_W1F_U32) {
        int sub = X & 3, lane = (X >> 2) & 63, f = X >> 8;
        int mt = f & 7, K32 = f >> 3;
        int o = mt * 16 + (lane & 15);
        int c = K32 * 32 + (lane >> 4) * 8 + sub * 2;
        float2 v = *(const float2*)(W1 + o * CIN_ + c);
        ws[X] = pack2bf(v.x, v.y);
    } else {
        int Y = X - (int)WS_W1F_U32;              // 0..5119
        int sub = Y & 3, lane = (Y >> 2) & 63, f = Y >> 8;
        int mt2 = f % 5, ks2 = f / 5;
        int o2 = mt2 * 16 + (lane & 15);
        int c = ks2 * 32 + (lane >> 4) * 8 + sub * 2;
        unsigned val = 0;
        if (o2 < OUTD_) {
            float2 v = *(const float2*)(W2 + o2 * HID_ + c);
            val = pack2bf(v.x, v.y);
        }
        ws[WS_W1F_U32 + Y] = val;
    }
}

// ---------------------------------------------------------------------------
// fused_main: block = (image, col-half), 512 thr = 8 waves; wave w = o-tile.
// GEMM1: barrier-free 40-step register stream, 4-deep rolling prefetch.
// LDS: smHT[32][68] (8,704 B). 2 blocks/CU.
// ---------------------------------------------------------------------------
__global__ __launch_bounds__(512, 4) void fused_main(
    const float* __restrict__ grd,   // (256,7,7,2)
    const float* __restrict__ bbox,  // (256,40,5)
    const float* __restrict__ anc,   // (9,2)
    const unsigned* __restrict__ wsW,
    const float* __restrict__ B1,    // (128,)
    const float* __restrict__ B2,    // (65,)
    float* __restrict__ out)
{
    __shared__ __align__(16) unsigned smHT[32 * 68];   // 8,704 B

    const int tid  = threadIdx.x;
    const int id   = blockIdx.x;
    const int b    = id >> 1;
    const int half = id & 1;
    const int lane = tid & 63;
    const int w    = tid >> 6;         // 0..7 = o-tile
    const int quad = lane >> 4;
    const int m16  = lane & 15;

    // A-frags: (k*8 + w)*64 + lane ; F-frags: b*10240 + k*256 + ct*64 + lane
    const uint4* Ap = (const uint4*)wsW + w * 64 + lane;             // +k*512
    const uint4* Fp = (const uint4*)(wsW + FB_OFF) + b * 10240 + half * 128 + lane;

    f32x4 acc[2] = {(f32x4)(0.f), (f32x4)(0.f)};
    uint4 ar[4], br[4][2];
    #pragma unroll
    for (int d = 0; d < 4; ++d) {
        ar[d]    = Ap[d * 512];
        br[d][0] = Fp[d * 256];
        br[d][1] = Fp[d * 256 + 64];
    }
    #pragma unroll
    for (int k = 0; k < 40; ++k) {               // full unroll: k&3 static
        const int s = k & 3;
        bf16x8 A = as_bf(ar[s]);
        acc[0] = __builtin_amdgcn_mfma_f32_16x16x32_bf16(A, as_bf(br[s][0]), acc[0], 0, 0, 0);
        acc[1] = __builtin_amdgcn_mfma_f32_16x16x32_bf16(A, as_bf(br[s][1]), acc[1], 0, 0, 0);
        const int kp = (k + 4 < 40) ? k + 4 : 39;
        ar[s]    = Ap[kp * 512];
        br[s][0] = Fp[kp * 256];
        br[s][1] = Fp[kp * 256 + 64];
    }

    // ---- h: bias + leaky -> smHT[colLocal*68 + o/2] (bf16 pairs) ----
    #pragma unroll
    for (int j = 0; j < 2; ++j) {
        int colL = j * 16 + m16;                 // 0..31 local col
        #pragma unroll
        for (int rp = 0; rp < 2; ++rp) {
            int o0 = w * 16 + quad * 4 + 2 * rp;
            float v0 = acc[j][2 * rp]     + B1[o0];
            float v1 = acc[j][2 * rp + 1] + B1[o0 + 1];
            v0 = v0 > 0.f ? v0 : 0.01f * v0;
            v1 = v1 > 0.f ? v1 : 0.01f * v1;
            smHT[colL * 68 + (o0 >> 1)] = pack2bf(v0, v1);
        }
    }
    __syncthreads();   // the only block-wide barrier

    // ---- GEMM2: 10 tiles (5 o2 x 2 ct); wave w: T = w, w+8 ----
    for (int T = w; T < 10; T += 8) {
        int m2 = T % 5, nt2 = T / 5;
        const uint4* A2p = (const uint4*)(wsW + WS_W1F_U32) + m2 * 64 + lane;
        uint4 a20 = A2p[0], a21 = A2p[320], a22 = A2p[640], a23 = A2p[960];
        f32x4 c2 = (f32x4)(0.f);
        const unsigned* Bb = smHT + (nt2 * 16 + m16) * 68 + quad * 4;
        c2 = __builtin_amdgcn_mfma_f32_16x16x32_bf16(as_bf(a20), ld_frag(Bb +  0), c2, 0, 0, 0);
        c2 = __builtin_amdgcn_mfma_f32_16x16x32_bf16(as_bf(a21), ld_frag(Bb + 16), c2, 0, 0, 0);
        c2 = __builtin_amdgcn_mfma_f32_16x16x32_bf16(as_bf(a22), ld_frag(Bb + 32), c2, 0, 0, 0);
        c2 = __builtin_amdgcn_mfma_f32_16x16x32_bf16(as_bf(a23), ld_frag(Bb + 48), c2, 0, 0, 0);
        int hw = half * 32 + nt2 * 16 + m16;
        if (hw < HW_) {
            #pragma unroll
            for (int r = 0; r < 4; ++r) {
                int o2 = m2 * 16 + quad * 4 + r;
                if (o2 >= OUTD_) continue;
                float aa = c2[r] + B2[o2];
                unsigned dst; float val;
                if (o2 < 36) {
                    int an9 = o2 >> 2, kk = o2 & 3;
                    val = (kk < 2) ? (sigmoidf_(aa) - 0.5f) : aa;
                    dst = OFFS_OFF + b * 1764 + an9 * 196 + kk * 49 + hw;
                } else if (o2 < 45) {
                    val = sigmoidf_(aa);
                    dst = CONF_OFF + b * 441 + (o2 - 36) * 49 + hw;
                } else {
                    val = aa;
                    dst = CLS_OFF + b * 980 + (o2 - 45) * 49 + hw;
                }
                out[dst] = val;
            }
        }
    }

    // ---- IoU: wave-uniform p, g = lane (<40), coalesced stores ----
    {
        int gl = (lane < NGT_) ? lane : 0;
        const float* gb = bbox + b * 200 + gl * 5;
        float gx1 = gb[0], gy1 = gb[1], gx2 = gb[2], gy2 = gb[3];
        float gA = (gx2 - gx1) * (gy2 - gy1);
        const int pstart = half ? 221 : 0;
        const int pend   = half ? NP_ : 221;
        #pragma unroll 4
        for (int p = pstart + w; p < pend; p += 8) {
            int a9 = p / 49, r = p - a9 * 49;
            float2 ct = *(const float2*)(grd + b * 98 + 2 * r);
            float hx = anc[2 * a9] * 0.5f,  hy = anc[2 * a9 + 1] * 0.5f;
            float px1 = ct.x - hx, py1 = ct.y - hy, px2 = ct.x + hx, py2 = ct.y + hy;
            float pA = (px2 - px1) * (py2 - py1);
            float legal = (fminf(fminf(px1, py1), fminf(px2, py2)) > 0.f) ? 1.f : 0.f;
            float tlx = fmaxf(px1, gx1), tly = fmaxf(py1, gy1);
            float brx = fminf(px2, gx2), bry = fminf(py2, gy2);
            float dx = fmaxf(brx - tlx, 0.f), dy = fmaxf(bry - tly, 0.f);
            float inter = dx * dy * legal;
            float iou = __fdividef(inter, gA + pA - inter);
            if (lane < NGT_)
                out[IOU_OFF + b * (NP_ * NGT_) + p * 40 + lane] = iou;
        }
    }
}

extern "C" void kernel_launch(void* const* d_in, const int* in_sizes, int n_in,
                              void* d_out, int out_size, void* d_ws, size_t ws_size,
                              hipStream_t stream) {
    const float* F  = (const float*)d_in[0];
    const float* G  = (const float*)d_in[1];
    const float* BB = (const float*)d_in[2];
    const float* AN = (const float*)d_in[3];
    const float* W1 = (const float*)d_in[4];
    const float* B1 = (const float*)d_in[5];
    const float* W2 = (const float*)d_in[6];
    const float* B2 = (const float*)d_in[7];
    float* out = (float*)d_out;
    unsigned* wsu = (unsigned*)d_ws;

    prep<<<10920, 128, 0, stream>>>(F, W1, W2, wsu);
    fused_main<<<512, 512, 0, stream>>>(G, BB, AN, wsu, B1, B2, out);
}